// Round 12
// baseline (406.769 us; speedup 1.0000x reference)
//
#include <hip/hip_runtime.h>

#define OUTN 8192
#define INN  4096
#define BN   128

namespace {

typedef __attribute__((ext_vector_type(8))) short bf16x8;   // 8 bf16 (4 VGPRs)
typedef __attribute__((ext_vector_type(4))) float f32x4;

struct alignas(16) f4 { float v[4]; };
struct alignas(8)  h4 { short v[4]; };

constexpr float C_HLOG2PI = 0.91893853f;   // 0.5*log(2*pi)
constexpr float C_LN2     = 0.69314718f;

__device__ __forceinline__ short f2bf(float f) {
    unsigned u = __float_as_uint(f);
    u += 0x7fffu + ((u >> 16) & 1u);       // round-to-nearest-even
    return (short)(u >> 16);
}

// ---- full-form helpers (bias path only) ----
__device__ __forceinline__ float prior_lp(float w) {
    float lp1 = -0.5f * w * w - C_HLOG2PI;
    float a   = w * 400.0f;
    float lp2 = -0.5f * a * a + 5.0725261f;
    return __logf(0.5f * __expf(lp1) + 0.5f * __expf(lp2));
}
__device__ __forceinline__ float post_lp(float w, float pi_, float s1, float ls1,
                                         float s2, float ls2) {
    float u1  = __fdividef(w, s1);
    float u2  = __fdividef(w, s2);
    float lq1 = -0.5f * u1 * u1 - ls1 - C_HLOG2PI;
    float lq2 = -0.5f * u2 * u2 - ls2 - C_HLOG2PI;
    return __logf(pi_ * __expf(lq1) + (1.0f - pi_) * __expf(lq2));
}
__device__ __forceinline__ float sample_w(float pi_, float rho1, float rho2, float ep,
                                          float g0, float g1,
                                          float& s1, float& ls1, float& s2, float& ls2) {
    s1  = __logf(1.0f + __expf(rho1));
    s2  = __logf(1.0f + __expf(rho2));
    ls1 = __logf(s1);
    ls2 = __logf(s2);
    bool mode1 = ((1.0f - pi_) + g1) > (pi_ + g0);
    return (mode1 ? s1 : s2) * ep;
}

constexpr int OT = 32;     // output rows per tile
constexpr int KC = 32;     // K-chunk (== MFMA K)
constexpr int NT = 256;
constexpr int KSTR = 40;   // bf16 LDS row stride (80 B: 16B-aligned, bank-spread)

// ---- fused prep: blocks 0..255 cast x->bf16; blocks 256..287 sample bias ----
__global__ __launch_bounds__(256)
void prep(const float* __restrict__ x, short* __restrict__ xb,
          const float* __restrict__ b_pi, const float* __restrict__ b_rho1,
          const float* __restrict__ b_rho2, const float* __restrict__ eps_b,
          const float* __restrict__ gum_b,
          float* __restrict__ bias_vals, float* __restrict__ bpart)
{
    __shared__ float red[8];
    const int tid = threadIdx.x;
    if (blockIdx.x < 256) {
        const int i = (blockIdx.x * 256 + tid) * 8;
        f4 a = *(const f4*)&x[i];
        f4 b = *(const f4*)&x[i + 4];
        h4 o0, o1;
        #pragma unroll
        for (int j = 0; j < 4; ++j) { o0.v[j] = f2bf(a.v[j]); o1.v[j] = f2bf(b.v[j]); }
        *(h4*)&xb[i]     = o0;
        *(h4*)&xb[i + 4] = o1;
        return;
    }
    const int bb = blockIdx.x - 256;           // 0..31
    const int o = bb * 256 + tid;
    float pi_ = b_pi[o], rho1 = b_rho1[o], rho2 = b_rho2[o], ep = eps_b[o];
    float g0 = gum_b[2*o], g1 = gum_b[2*o + 1];
    float s1, ls1, s2, ls2;
    float w = sample_w(pi_, rho1, rho2, ep, g0, g1, s1, ls1, s2, ls2);
    bias_vals[o] = w;
    float pa = prior_lp(w);
    float qa = post_lp(w, pi_, s1, ls1, s2, ls2);
    #pragma unroll
    for (int off = 32; off; off >>= 1) {
        pa += __shfl_down(pa, off);
        qa += __shfl_down(qa, off);
    }
    const int wave = tid >> 6;
    if ((tid & 63) == 0) { red[wave] = pa; red[4 + wave] = qa; }
    __syncthreads();
    if (tid == 0) {
        bpart[2*bb    ] = red[0] + red[1] + red[2] + red[3];
        bpart[2*bb + 1] = red[4] + red[5] + red[6] + red[7];
    }
}

// R8 skeleton, SINGLE-barrier double-buffered variant (same register depth):
//   sample(t) -> stage buf[t&1] -> issue loads(t+1) -> __syncthreads -> MFMA(t)
// The compiler's vmcnt(0) drain at __syncthreads completes the t+1 loads AT
// THE BARRIER (where other resident blocks cover the dwell) instead of
// mid-sample on the VALU critical path (R8: only ~100cy MFMA cover -> ~700cy
// stall inside sample). WAR on buf[p]: a wave reaches stage(t+2) only after
// B(t+1), which all waves pass only after their MFMA(t) reads -> safe.
// Registers identical to R8 (one stream generation) -> no spill (R10/R11
// lesson: >~64 total VGPRs spills under these bounds).
__global__ __launch_bounds__(NT, 6)
void bayes_main(const short* __restrict__ xb,      // x in bf16, [BN][INN]
                const float* __restrict__ w_pi,
                const float* __restrict__ w_rho1,
                const float* __restrict__ w_rho2,
                const float* __restrict__ eps_w,
                const float* __restrict__ gum_w,
                const float* __restrict__ bias,    // non-null only when NS==1
                float* __restrict__ out,
                float* __restrict__ pbuf,
                float* __restrict__ partials,
                int NS)
{
    __shared__ alignas(16) short Wt[2][OT][KSTR];   // W tile [o][k] bf16
    __shared__ alignas(16) short Xs[2][BN][KSTR];   // x tile [b][k] bf16
    __shared__ float red[8];

    const int tid   = threadIdx.x;
    const int split = blockIdx.x >> 8;
    const int tile  = blockIdx.x & 255;
    const int o0    = tile * OT;

    // non-uniform K-split: 128 chunks over NS splits
    const int baseCh = 128 / NS;
    const int remCh  = 128 % NS;
    const int nch    = baseCh + (split < remCh ? 1 : 0);
    const int ch0    = split * baseCh + (split < remCh ? split : remCh);
    const int k0     = ch0 * KC;

    float* outp = (split == 0) ? out : pbuf + (size_t)(split - 1) * ((size_t)BN * OUTN);

    const int c = tid & 7;     // k-quad index
    const int r = tid >> 3;    // o-row index 0..31

    const size_t wbase = (size_t)(o0 + r) * INN + k0;
    const f4* pi4 = (const f4*)(w_pi   + wbase) + c;
    const f4* r14 = (const f4*)(w_rho1 + wbase) + c;
    const f4* r24 = (const f4*)(w_rho2 + wbase) + c;
    const f4* ep4 = (const f4*)(eps_w  + wbase) + c;
    const f4* gm4 = (const f4*)(gum_w  + 2 * wbase) + 2 * c;

    // x staging: thread covers row xrr, 16-short half xcc
    const int xrr = tid >> 1;           // 0..127
    const int xcc = (tid & 1) * 16;     // 0 or 16
    const short* xsrc = xb + (size_t)xrr * INN + k0 + xcc;

    f32x4 acc00 = {0.f,0.f,0.f,0.f}, acc01 = {0.f,0.f,0.f,0.f};
    f32x4 acc10 = {0.f,0.f,0.f,0.f}, acc11 = {0.f,0.f,0.f,0.f};
    float priorAcc = 0.0f, postAcc = 0.0f;

    // MFMA lane geometry
    const int wv_  = tid >> 6;          // wave 0..3 -> b-slice 32*wv_
    const int lane = tid & 63;
    const int lrow = lane & 15;
    const int lgo  = (lane >> 4) * 8;   // bf16 col offset of this lane's frag

    // prologue prefetch: chunk 0
    f4 vpi = pi4[0], vr1 = r14[0], vr2 = r24[0], vep = ep4[0];
    f4 vga = gm4[0], vgb = gm4[1];
    bf16x8 xv0 = *(const bf16x8*)(xsrc);
    bf16x8 xv1 = *(const bf16x8*)(xsrc + 8);

    #pragma unroll 1
    for (int t = 0; t < nch; ++t) {
        const int p = t & 1;

        // --- sample 4 weights + accumulate log-probs (loads for t completed
        //     at barrier t-1: no mid-sample vmcnt stall) ---
        h4 wb;
        #pragma unroll
        for (int i = 0; i < 4; ++i) {
            const f4& g = (i < 2) ? vga : vgb;
            float g0 = g.v[(i & 1) * 2], g1 = g.v[(i & 1) * 2 + 1];
            float pi_ = vpi.v[i], ep = vep.v[i];
            float s1  = __logf(1.0f + __expf(vr1.v[i]));
            float s2  = __logf(1.0f + __expf(vr2.v[i]));
            float ls1 = __logf(s1), ls2 = __logf(s2);
            bool  m1  = ((1.0f - pi_) + g1) > (pi_ + g0);
            float sm  = m1 ? s1 : s2;
            float so  = m1 ? s2 : s1;
            float lsm = m1 ? ls1 : ls2;
            float lso = m1 ? ls2 : ls1;
            float wm  = m1 ? pi_ : 1.0f - pi_;
            float w   = sm * ep;
            wb.v[i] = f2bf(w);
            float wsq = w * w;
            float dlp = 5.9914645f - 79999.5f * wsq;
            priorAcc += -0.5f * wsq + __logf(1.0f + __expf(dlp));   // -C-ln2 folded
            float uo   = __fdividef(w, so);
            float epsq = ep * ep;
            float dlq  = 0.5f * (epsq - uo * uo) + (lsm - lso);
            postAcc += -0.5f * epsq - lsm
                       + __logf(wm + (1.0f - wm) * __expf(dlq));    // -C folded
        }

        // --- stage chunk t into buf p (no barrier needed before: buf p was
        //     last read at MFMA(t-2), ordered by barrier t-1) ---
        *(h4*)&Wt[p][r][4 * c] = wb;
        *(bf16x8*)&Xs[p][xrr][xcc]     = xv0;
        *(bf16x8*)&Xs[p][xrr][xcc + 8] = xv1;

        // --- issue loads for t+1 BEFORE the barrier: the barrier's vmcnt
        //     drain completes them here, where other blocks cover the dwell ---
        if (t + 1 < nch) {
            const int tn = t + 1;
            vpi = pi4[8*tn]; vr1 = r14[8*tn]; vr2 = r24[8*tn]; vep = ep4[8*tn];
            vga = gm4[16*tn]; vgb = gm4[16*tn + 1];
            xv0 = *(const bf16x8*)(xsrc + 32*tn);
            xv1 = *(const bf16x8*)(xsrc + 32*tn + 8);
        }

        __syncthreads();    // single barrier: ds_writes visible + loads drained

        // --- MFMA: A = x tile (M=b), B = W tile (N=o), K=32 ---
        bf16x8 a0 = *(const bf16x8*)&Xs[p][32 * wv_      + lrow][lgo];
        bf16x8 a1 = *(const bf16x8*)&Xs[p][32 * wv_ + 16 + lrow][lgo];
        bf16x8 b0 = *(const bf16x8*)&Wt[p][lrow     ][lgo];
        bf16x8 b1 = *(const bf16x8*)&Wt[p][16 + lrow][lgo];
        acc00 = __builtin_amdgcn_mfma_f32_16x16x32_bf16(a0, b0, acc00, 0, 0, 0);
        acc01 = __builtin_amdgcn_mfma_f32_16x16x32_bf16(a0, b1, acc01, 0, 0, 0);
        acc10 = __builtin_amdgcn_mfma_f32_16x16x32_bf16(a1, b0, acc10, 0, 0, 0);
        acc11 = __builtin_amdgcn_mfma_f32_16x16x32_bf16(a1, b1, acc11, 0, 0, 0);
    }

    // fold per-element constants: prior -(C+ln2), post -C, 4*nch elems/thread
    {
        const float ne = (float)(4 * nch);
        priorAcc -= ne * (C_HLOG2PI + C_LN2);
        postAcc  -= ne * C_HLOG2PI;
    }

    // epilogue: C/D layout col=lane&15 (o), row=(lane>>4)*4+reg (b)
    {
        const int oc = o0 + lrow;
        const int bb = 32 * wv_ + (lane >> 4) * 4;
        const float bv0 = bias ? bias[oc]      : 0.0f;
        const float bv1 = bias ? bias[oc + 16] : 0.0f;
        #pragma unroll
        for (int j = 0; j < 4; ++j) {
            outp[(size_t)(bb      + j) * OUTN + oc     ] = acc00[j] + bv0;
            outp[(size_t)(bb      + j) * OUTN + oc + 16] = acc01[j] + bv1;
            outp[(size_t)(bb + 16 + j) * OUTN + oc     ] = acc10[j] + bv0;
            outp[(size_t)(bb + 16 + j) * OUTN + oc + 16] = acc11[j] + bv1;
        }
    }

    // deterministic block reduction of log-prob partials
    #pragma unroll
    for (int off = 32; off; off >>= 1) {
        priorAcc += __shfl_down(priorAcc, off);
        postAcc  += __shfl_down(postAcc, off);
    }
    if ((tid & 63) == 0) { red[wv_] = priorAcc; red[4 + wv_] = postAcc; }
    __syncthreads();
    if (tid == 0) {
        partials[2*blockIdx.x    ] = red[0] + red[1] + red[2] + red[3];
        partials[2*blockIdx.x + 1] = red[4] + red[5] + red[6] + red[7];
    }
}

// ---- fused reduce + final (block 0 also reduces the log-prob partials) ----
__global__ __launch_bounds__(256)
void reduce_final(float* __restrict__ out, const float* __restrict__ pbuf,
                  const float* __restrict__ bias, int nsplit,
                  const float* __restrict__ partials, int cnt,
                  float* __restrict__ out_scalars)
{
    const int tid = threadIdx.x;
    const size_t i = ((size_t)blockIdx.x * 256 + tid) * 4;   // 1024 blocks
    const int o = (int)(i & (OUTN - 1));
    f4 a  = *(const f4*)&out[i];
    f4 bq = *(const f4*)&bias[o];
    #pragma unroll 1
    for (int s = 0; s < nsplit - 1; ++s) {
        f4 p = *(const f4*)&pbuf[(size_t)s * ((size_t)BN * OUTN) + i];
        #pragma unroll
        for (int j = 0; j < 4; ++j) a.v[j] += p.v[j];
    }
    #pragma unroll
    for (int j = 0; j < 4; ++j) a.v[j] += bq.v[j];
    *(f4*)&out[i] = a;

    if (blockIdx.x == 0) {
        __shared__ double sp[4], sq[4];
        double p = 0.0, q = 0.0;
        for (int j = tid; j < cnt; j += 256) {
            p += (double)partials[2*j];
            q += (double)partials[2*j + 1];
        }
        #pragma unroll
        for (int off = 32; off; off >>= 1) {
            p += __shfl_down(p, off);
            q += __shfl_down(q, off);
        }
        const int wave = tid >> 6;
        if ((tid & 63) == 0) { sp[wave] = p; sq[wave] = q; }
        __syncthreads();
        if (tid == 0) {
            out_scalars[0] = (float)(sp[0] + sp[1] + sp[2] + sp[3]);
            out_scalars[1] = (float)(sq[0] + sq[1] + sq[2] + sq[3]);
        }
    }
}

// NS==1 fallback final (no reduce pass)
__global__ __launch_bounds__(256)
void bayes_final(const float* __restrict__ partials, int cnt,
                 float* __restrict__ out_scalars)
{
    __shared__ double sp[4], sq[4];
    const int tid = threadIdx.x;
    double p = 0.0, q = 0.0;
    for (int j = tid; j < cnt; j += 256) {
        p += (double)partials[2*j];
        q += (double)partials[2*j + 1];
    }
    #pragma unroll
    for (int off = 32; off; off >>= 1) {
        p += __shfl_down(p, off);
        q += __shfl_down(q, off);
    }
    const int wave = tid >> 6;
    if ((tid & 63) == 0) { sp[wave] = p; sq[wave] = q; }
    __syncthreads();
    if (tid == 0) {
        out_scalars[0] = (float)(sp[0] + sp[1] + sp[2] + sp[3]);
        out_scalars[1] = (float)(sq[0] + sq[1] + sq[2] + sq[3]);
    }
}

} // namespace

extern "C" void kernel_launch(void* const* d_in, const int* in_sizes, int n_in,
                              void* d_out, int out_size, void* d_ws, size_t ws_size,
                              hipStream_t stream) {
    (void)in_sizes; (void)n_in; (void)out_size;
    const float* x      = (const float*)d_in[0];
    const float* w_pi   = (const float*)d_in[1];
    const float* w_rho1 = (const float*)d_in[2];
    const float* w_rho2 = (const float*)d_in[3];
    const float* b_pi   = (const float*)d_in[4];
    const float* b_rho1 = (const float*)d_in[5];
    const float* b_rho2 = (const float*)d_in[6];
    const float* eps_w  = (const float*)d_in[7];
    const float* eps_b  = (const float*)d_in[8];
    const float* gum_w  = (const float*)d_in[9];
    const float* gum_b  = (const float*)d_in[10];

    float* out = (float*)d_out;
    float* ws  = (float*)d_ws;
    // ws layout (floats):
    //   [0, 8192)           bias values
    //   [8192, 16384)       logp partials: main blocks (2*256*NS), then bias blocks
    //   [16384, 540672)     x in bf16 (524288 shorts)
    //   [540672, ...)       (NS-1) partial GEMM outputs, 1048576 floats each
    float* bias_vals = ws;
    float* partials  = ws + 8192;
    short* xb        = (short*)(ws + 16384);
    float* pbuf      = ws + 540672;

    const size_t outElems = (size_t)BN * OUTN;
    int NS = 1;
    if      (ws_size >= (540672 + 5 * outElems) * sizeof(float)) NS = 6;
    else if (ws_size >= (540672 + 3 * outElems) * sizeof(float)) NS = 4;
    else if (ws_size >= (540672 + 1 * outElems) * sizeof(float)) NS = 2;

    float* bpart = partials + 2 * 256 * NS;
    const int cnt = 256 * NS + 32;

    prep<<<288, 256, 0, stream>>>(x, xb, b_pi, b_rho1, b_rho2, eps_b, gum_b,
                                  bias_vals, bpart);

    if (NS == 1) {
        bayes_main<<<256, NT, 0, stream>>>(xb, w_pi, w_rho1, w_rho2, eps_w, gum_w,
                                           bias_vals, out, pbuf, partials, 1);
        bayes_final<<<1, 256, 0, stream>>>(partials, cnt, out + outElems);
    } else {
        bayes_main<<<256 * NS, NT, 0, stream>>>(xb, w_pi, w_rho1, w_rho2, eps_w, gum_w,
                                                nullptr, out, pbuf, partials, NS);
        reduce_final<<<(int)(outElems / 4 / 256), 256, 0, stream>>>(
            out, pbuf, bias_vals, NS, partials, cnt, out + outElems);
    }
}

// Round 13
// 225.642 us; speedup vs baseline: 1.8027x; 1.8027x over previous
//
#include <hip/hip_runtime.h>

#define OUTN 8192
#define INN  4096
#define BN   128

namespace {

typedef __attribute__((ext_vector_type(8))) short bf16x8;   // 8 bf16 (4 VGPRs)
typedef __attribute__((ext_vector_type(4))) float f32x4;

struct alignas(16) f4 { float v[4]; };
struct alignas(8)  h4 { short v[4]; };

constexpr float C_HLOG2PI = 0.91893853f;   // 0.5*log(2*pi)
constexpr float C_LN2     = 0.69314718f;

__device__ __forceinline__ short f2bf(float f) {
    unsigned u = __float_as_uint(f);
    u += 0x7fffu + ((u >> 16) & 1u);       // round-to-nearest-even
    return (short)(u >> 16);
}

// ---- full-form helpers (bias logp path only) ----
__device__ __forceinline__ float prior_lp(float w) {
    float lp1 = -0.5f * w * w - C_HLOG2PI;
    float a   = w * 400.0f;
    float lp2 = -0.5f * a * a + 5.0725261f;
    return __logf(0.5f * __expf(lp1) + 0.5f * __expf(lp2));
}
__device__ __forceinline__ float post_lp(float w, float pi_, float s1, float ls1,
                                         float s2, float ls2) {
    float u1  = __fdividef(w, s1);
    float u2  = __fdividef(w, s2);
    float lq1 = -0.5f * u1 * u1 - ls1 - C_HLOG2PI;
    float lq2 = -0.5f * u2 * u2 - ls2 - C_HLOG2PI;
    return __logf(pi_ * __expf(lq1) + (1.0f - pi_) * __expf(lq2));
}
__device__ __forceinline__ float sample_w(float pi_, float rho1, float rho2, float ep,
                                          float g0, float g1,
                                          float& s1, float& ls1, float& s2, float& ls2) {
    s1  = __logf(1.0f + __expf(rho1));
    s2  = __logf(1.0f + __expf(rho2));
    ls1 = __logf(s1);
    ls2 = __logf(s2);
    bool mode1 = ((1.0f - pi_) + g1) > (pi_ + g0);
    return (mode1 ? s1 : s2) * ep;
}
// value-only sampler (epilogue bias: no logp needed)
__device__ __forceinline__ float sample_val(float pi_, float r1, float r2, float ep,
                                            float g0, float g1) {
    float s1 = __logf(1.0f + __expf(r1));
    float s2 = __logf(1.0f + __expf(r2));
    bool  m1 = ((1.0f - pi_) + g1) > (pi_ + g0);
    return (m1 ? s1 : s2) * ep;
}

constexpr int OT = 32;     // output rows per tile
constexpr int KC = 32;     // K-chunk (== MFMA K)
constexpr int NT = 256;
constexpr int KSTR = 40;   // bf16 LDS row stride (80 B: 16B-aligned, bank-spread)

// ---- NS==1 fallback only: bias values + logp partials ----
__global__ __launch_bounds__(256)
void bias_only(const float* __restrict__ b_pi, const float* __restrict__ b_rho1,
               const float* __restrict__ b_rho2, const float* __restrict__ eps_b,
               const float* __restrict__ gum_b,
               float* __restrict__ bias_vals, float* __restrict__ bpart)
{
    __shared__ float red[8];
    const int tid = threadIdx.x;
    const int o = blockIdx.x * 256 + tid;      // 32 blocks x 256 = 8192
    float pi_ = b_pi[o], rho1 = b_rho1[o], rho2 = b_rho2[o], ep = eps_b[o];
    float g0 = gum_b[2*o], g1 = gum_b[2*o + 1];
    float s1, ls1, s2, ls2;
    float w = sample_w(pi_, rho1, rho2, ep, g0, g1, s1, ls1, s2, ls2);
    bias_vals[o] = w;
    float pa = prior_lp(w);
    float qa = post_lp(w, pi_, s1, ls1, s2, ls2);
    #pragma unroll
    for (int off = 32; off; off >>= 1) {
        pa += __shfl_down(pa, off);
        qa += __shfl_down(qa, off);
    }
    const int wave = tid >> 6;
    if ((tid & 63) == 0) { red[wave] = pa; red[4 + wave] = qa; }
    __syncthreads();
    if (tid == 0) {
        bpart[2*blockIdx.x    ] = red[0] + red[1] + red[2] + red[3];
        bpart[2*blockIdx.x + 1] = red[4] + red[5] + red[6] + red[7];
    }
}

// R8 champion skeleton VERBATIM (schedule, barriers, LDS layout, load
// placement untouched — 5 restructuring attempts all spilled). Only change:
// x is read f32 directly (4xf4/thread/chunk, L2-resident) and cast to bf16
// at stage time — deletes the serial xcast prep pass. +8 VGPR prefetch
// (tripwire: WRITE_SIZE jump = spill = revert).
__global__ __launch_bounds__(NT, 6)
void bayes_main(const float* __restrict__ x,       // x f32, [BN][INN]
                const float* __restrict__ w_pi,
                const float* __restrict__ w_rho1,
                const float* __restrict__ w_rho2,
                const float* __restrict__ eps_w,
                const float* __restrict__ gum_w,
                const float* __restrict__ bias,    // non-null only when NS==1
                float* __restrict__ out,
                float* __restrict__ pbuf,
                float* __restrict__ partials,
                int NS)
{
    __shared__ alignas(16) short Wt[OT][KSTR];   // W tile [o][k] bf16
    __shared__ alignas(16) short Xs[BN][KSTR];   // x tile [b][k] bf16
    __shared__ float red[8];

    const int tid   = threadIdx.x;
    const int split = blockIdx.x >> 8;
    const int tile  = blockIdx.x & 255;
    const int o0    = tile * OT;

    // non-uniform K-split: 128 chunks over NS splits
    const int baseCh = 128 / NS;
    const int remCh  = 128 % NS;
    const int nch    = baseCh + (split < remCh ? 1 : 0);
    const int ch0    = split * baseCh + (split < remCh ? split : remCh);
    const int k0     = ch0 * KC;

    float* outp = (split == 0) ? out : pbuf + (size_t)(split - 1) * ((size_t)BN * OUTN);

    const int c = tid & 7;     // k-quad index
    const int r = tid >> 3;    // o-row index 0..31

    const size_t wbase = (size_t)(o0 + r) * INN + k0;
    const f4* pi4 = (const f4*)(w_pi   + wbase) + c;
    const f4* r14 = (const f4*)(w_rho1 + wbase) + c;
    const f4* r24 = (const f4*)(w_rho2 + wbase) + c;
    const f4* ep4 = (const f4*)(eps_w  + wbase) + c;
    const f4* gm4 = (const f4*)(gum_w  + 2 * wbase) + 2 * c;

    // x staging: thread covers row xrr, 16-element half xcc (f32 source)
    const int xrr = tid >> 1;           // 0..127
    const int xcc = (tid & 1) * 16;     // 0 or 16
    const float* xsrc = x + (size_t)xrr * INN + k0 + xcc;

    f32x4 acc00 = {0.f,0.f,0.f,0.f}, acc01 = {0.f,0.f,0.f,0.f};
    f32x4 acc10 = {0.f,0.f,0.f,0.f}, acc11 = {0.f,0.f,0.f,0.f};
    float priorAcc = 0.0f, postAcc = 0.0f;

    // MFMA lane geometry
    const int wv_  = tid >> 6;          // wave 0..3 -> b-slice 32*wv_
    const int lane = tid & 63;
    const int lrow = lane & 15;
    const int lgo  = (lane >> 4) * 8;   // bf16 col offset of this lane's frag

    // prologue prefetch: chunk 0
    f4 vpi = pi4[0], vr1 = r14[0], vr2 = r24[0], vep = ep4[0];
    f4 vga = gm4[0], vgb = gm4[1];
    f4 xa0 = *(const f4*)(xsrc);
    f4 xa1 = *(const f4*)(xsrc + 4);
    f4 xa2 = *(const f4*)(xsrc + 8);
    f4 xa3 = *(const f4*)(xsrc + 12);

    #pragma unroll 1
    for (int t = 0; t < nch; ++t) {
        // --- sample 4 weights + accumulate log-probs (LSE, consts folded) ---
        h4 wb;
        #pragma unroll
        for (int i = 0; i < 4; ++i) {
            const f4& g = (i < 2) ? vga : vgb;
            float g0 = g.v[(i & 1) * 2], g1 = g.v[(i & 1) * 2 + 1];
            float pi_ = vpi.v[i], ep = vep.v[i];
            float s1  = __logf(1.0f + __expf(vr1.v[i]));
            float s2  = __logf(1.0f + __expf(vr2.v[i]));
            float ls1 = __logf(s1), ls2 = __logf(s2);
            bool  m1  = ((1.0f - pi_) + g1) > (pi_ + g0);
            float sm  = m1 ? s1 : s2;
            float so  = m1 ? s2 : s1;
            float lsm = m1 ? ls1 : ls2;
            float lso = m1 ? ls2 : ls1;
            float wm  = m1 ? pi_ : 1.0f - pi_;
            float w   = sm * ep;
            wb.v[i] = f2bf(w);
            float wsq = w * w;
            float dlp = 5.9914645f - 79999.5f * wsq;
            priorAcc += -0.5f * wsq + __logf(1.0f + __expf(dlp));   // -C-ln2 folded
            float uo   = __fdividef(w, so);
            float epsq = ep * ep;
            float dlq  = 0.5f * (epsq - uo * uo) + (lsm - lso);
            postAcc += -0.5f * epsq - lsm
                       + __logf(wm + (1.0f - wm) * __expf(dlq));    // -C folded
        }

        __syncthreads();             // previous chunk's frag reads done
        *(h4*)&Wt[r][4 * c] = wb;
        {
            bf16x8 xb0, xb1;
            #pragma unroll
            for (int j = 0; j < 4; ++j) {
                xb0[j]     = f2bf(xa0.v[j]);
                xb0[4 + j] = f2bf(xa1.v[j]);
                xb1[j]     = f2bf(xa2.v[j]);
                xb1[4 + j] = f2bf(xa3.v[j]);
            }
            *(bf16x8*)&Xs[xrr][xcc]     = xb0;
            *(bf16x8*)&Xs[xrr][xcc + 8] = xb1;
        }
        __syncthreads();             // tiles ready

        // --- prefetch t+1 (after barrier 2, exactly as R8: latency covered
        //     by MFMA phase + other resident blocks) ---
        const int tn = (t + 1 < nch) ? t + 1 : 0;
        vpi = pi4[8*tn]; vr1 = r14[8*tn]; vr2 = r24[8*tn]; vep = ep4[8*tn];
        vga = gm4[16*tn]; vgb = gm4[16*tn + 1];
        xa0 = *(const f4*)(xsrc + 32*tn);
        xa1 = *(const f4*)(xsrc + 32*tn + 4);
        xa2 = *(const f4*)(xsrc + 32*tn + 8);
        xa3 = *(const f4*)(xsrc + 32*tn + 12);

        // --- MFMA: A = x tile (M=b), B = W tile (N=o), K=32 ---
        bf16x8 a0 = *(const bf16x8*)&Xs[32 * wv_      + lrow][lgo];
        bf16x8 a1 = *(const bf16x8*)&Xs[32 * wv_ + 16 + lrow][lgo];
        bf16x8 b0 = *(const bf16x8*)&Wt[lrow     ][lgo];
        bf16x8 b1 = *(const bf16x8*)&Wt[16 + lrow][lgo];
        acc00 = __builtin_amdgcn_mfma_f32_16x16x32_bf16(a0, b0, acc00, 0, 0, 0);
        acc01 = __builtin_amdgcn_mfma_f32_16x16x32_bf16(a0, b1, acc01, 0, 0, 0);
        acc10 = __builtin_amdgcn_mfma_f32_16x16x32_bf16(a1, b0, acc10, 0, 0, 0);
        acc11 = __builtin_amdgcn_mfma_f32_16x16x32_bf16(a1, b1, acc11, 0, 0, 0);
    }

    // fold per-element constants: prior -(C+ln2), post -C, 4*nch elems/thread
    {
        const float ne = (float)(4 * nch);
        priorAcc -= ne * (C_HLOG2PI + C_LN2);
        postAcc  -= ne * C_HLOG2PI;
    }

    // epilogue: C/D layout col=lane&15 (o), row=(lane>>4)*4+reg (b)
    {
        const int oc = o0 + lrow;
        const int bb = 32 * wv_ + (lane >> 4) * 4;
        const float bv0 = bias ? bias[oc]      : 0.0f;
        const float bv1 = bias ? bias[oc + 16] : 0.0f;
        #pragma unroll
        for (int j = 0; j < 4; ++j) {
            outp[(size_t)(bb      + j) * OUTN + oc     ] = acc00[j] + bv0;
            outp[(size_t)(bb      + j) * OUTN + oc + 16] = acc01[j] + bv1;
            outp[(size_t)(bb + 16 + j) * OUTN + oc     ] = acc10[j] + bv0;
            outp[(size_t)(bb + 16 + j) * OUTN + oc + 16] = acc11[j] + bv1;
        }
    }

    // deterministic block reduction of log-prob partials
    #pragma unroll
    for (int off = 32; off; off >>= 1) {
        priorAcc += __shfl_down(priorAcc, off);
        postAcc  += __shfl_down(postAcc, off);
    }
    if ((tid & 63) == 0) { red[wv_] = priorAcc; red[4 + wv_] = postAcc; }
    __syncthreads();
    if (tid == 0) {
        partials[2*blockIdx.x    ] = red[0] + red[1] + red[2] + red[3];
        partials[2*blockIdx.x + 1] = red[4] + red[5] + red[6] + red[7];
    }
}

// ---- fused reduce + bias + final ----
// blocks 0..1023: out[i] = sum(partial outs) + bias(o) (bias sampled locally,
//                 value-only). block 1024: bias logp sum + final scalars.
__global__ __launch_bounds__(256)
void reduce_final(float* __restrict__ out, const float* __restrict__ pbuf,
                  int nsplit, const float* __restrict__ partials, int npart,
                  const float* __restrict__ b_pi, const float* __restrict__ b_rho1,
                  const float* __restrict__ b_rho2, const float* __restrict__ eps_b,
                  const float* __restrict__ gum_b,
                  float* __restrict__ out_scalars)
{
    const int tid = threadIdx.x;

    if (blockIdx.x == 1024) {
        // bias log-probs (deterministic fixed-stride accumulation)
        __shared__ float red[8];
        __shared__ double sp[4], sq[4];
        float pa = 0.0f, qa = 0.0f;
        for (int o = tid; o < OUTN; o += 256) {
            float s1, ls1, s2, ls2;
            float w = sample_w(b_pi[o], b_rho1[o], b_rho2[o], eps_b[o],
                               gum_b[2*o], gum_b[2*o + 1], s1, ls1, s2, ls2);
            pa += prior_lp(w);
            qa += post_lp(w, b_pi[o], s1, ls1, s2, ls2);
        }
        #pragma unroll
        for (int off = 32; off; off >>= 1) {
            pa += __shfl_down(pa, off);
            qa += __shfl_down(qa, off);
        }
        const int wave = tid >> 6;
        if ((tid & 63) == 0) { red[wave] = pa; red[4 + wave] = qa; }

        // main-kernel partials in double
        double p = 0.0, q = 0.0;
        for (int j = tid; j < npart; j += 256) {
            p += (double)partials[2*j];
            q += (double)partials[2*j + 1];
        }
        #pragma unroll
        for (int off = 32; off; off >>= 1) {
            p += __shfl_down(p, off);
            q += __shfl_down(q, off);
        }
        if ((tid & 63) == 0) { sp[wave] = p; sq[wave] = q; }
        __syncthreads();
        if (tid == 0) {
            double bp = (double)(red[0] + red[1] + red[2] + red[3]);
            double bq = (double)(red[4] + red[5] + red[6] + red[7]);
            out_scalars[0] = (float)(sp[0] + sp[1] + sp[2] + sp[3] + bp);
            out_scalars[1] = (float)(sq[0] + sq[1] + sq[2] + sq[3] + bq);
        }
        return;
    }

    const size_t i = ((size_t)blockIdx.x * 256 + tid) * 4;
    const int o = (int)(i & (OUTN - 1));

    // sample this thread's 4 bias values (value-only: 2 exp + 2 log each)
    f4 bp = *(const f4*)&b_pi[o];
    f4 b1 = *(const f4*)&b_rho1[o];
    f4 b2 = *(const f4*)&b_rho2[o];
    f4 be = *(const f4*)&eps_b[o];
    f4 g01 = *(const f4*)&gum_b[2*o];
    f4 g23 = *(const f4*)&gum_b[2*o + 4];
    f4 bw;
    #pragma unroll
    for (int j = 0; j < 4; ++j) {
        const f4& g = (j < 2) ? g01 : g23;
        bw.v[j] = sample_val(bp.v[j], b1.v[j], b2.v[j], be.v[j],
                             g.v[(j & 1) * 2], g.v[(j & 1) * 2 + 1]);
    }

    f4 a = *(const f4*)&out[i];
    #pragma unroll 1
    for (int s = 0; s < nsplit - 1; ++s) {
        f4 p = *(const f4*)&pbuf[(size_t)s * ((size_t)BN * OUTN) + i];
        #pragma unroll
        for (int j = 0; j < 4; ++j) a.v[j] += p.v[j];
    }
    #pragma unroll
    for (int j = 0; j < 4; ++j) a.v[j] += bw.v[j];
    *(f4*)&out[i] = a;
}

// NS==1 fallback final (no reduce pass; bias partials from bias_only)
__global__ __launch_bounds__(256)
void bayes_final(const float* __restrict__ partials, int cnt,
                 float* __restrict__ out_scalars)
{
    __shared__ double sp[4], sq[4];
    const int tid = threadIdx.x;
    double p = 0.0, q = 0.0;
    for (int j = tid; j < cnt; j += 256) {
        p += (double)partials[2*j];
        q += (double)partials[2*j + 1];
    }
    #pragma unroll
    for (int off = 32; off; off >>= 1) {
        p += __shfl_down(p, off);
        q += __shfl_down(q, off);
    }
    const int wave = tid >> 6;
    if ((tid & 63) == 0) { sp[wave] = p; sq[wave] = q; }
    __syncthreads();
    if (tid == 0) {
        out_scalars[0] = (float)(sp[0] + sp[1] + sp[2] + sp[3]);
        out_scalars[1] = (float)(sq[0] + sq[1] + sq[2] + sq[3]);
    }
}

} // namespace

extern "C" void kernel_launch(void* const* d_in, const int* in_sizes, int n_in,
                              void* d_out, int out_size, void* d_ws, size_t ws_size,
                              hipStream_t stream) {
    (void)in_sizes; (void)n_in; (void)out_size;
    const float* x      = (const float*)d_in[0];
    const float* w_pi   = (const float*)d_in[1];
    const float* w_rho1 = (const float*)d_in[2];
    const float* w_rho2 = (const float*)d_in[3];
    const float* b_pi   = (const float*)d_in[4];
    const float* b_rho1 = (const float*)d_in[5];
    const float* b_rho2 = (const float*)d_in[6];
    const float* eps_w  = (const float*)d_in[7];
    const float* eps_b  = (const float*)d_in[8];
    const float* gum_w  = (const float*)d_in[9];
    const float* gum_b  = (const float*)d_in[10];

    float* out = (float*)d_out;
    float* ws  = (float*)d_ws;
    // ws layout (floats):
    //   [0, 8192)           bias values (NS==1 fallback only)
    //   [8192, 16384)       logp partials: main blocks (2*256*NS), then bias blocks
    //   [540672, ...)       (NS-1) partial GEMM outputs, 1048576 floats each
    float* bias_vals = ws;
    float* partials  = ws + 8192;
    float* pbuf      = ws + 540672;

    const size_t outElems = (size_t)BN * OUTN;
    int NS = 1;
    if      (ws_size >= (540672 + 5 * outElems) * sizeof(float)) NS = 6;
    else if (ws_size >= (540672 + 3 * outElems) * sizeof(float)) NS = 4;
    else if (ws_size >= (540672 + 1 * outElems) * sizeof(float)) NS = 2;

    if (NS == 1) {
        float* bpart = partials + 2 * 256;
        bias_only<<<32, 256, 0, stream>>>(b_pi, b_rho1, b_rho2, eps_b, gum_b,
                                          bias_vals, bpart);
        bayes_main<<<256, NT, 0, stream>>>(x, w_pi, w_rho1, w_rho2, eps_w, gum_w,
                                           bias_vals, out, pbuf, partials, 1);
        bayes_final<<<1, 256, 0, stream>>>(partials, 256 + 32, out + outElems);
    } else {
        bayes_main<<<256 * NS, NT, 0, stream>>>(x, w_pi, w_rho1, w_rho2, eps_w, gum_w,
                                                nullptr, out, pbuf, partials, NS);
        reduce_final<<<(int)(outElems / 4 / 256) + 1, 256, 0, stream>>>(
            out, pbuf, NS, partials, 256 * NS,
            b_pi, b_rho1, b_rho2, eps_b, gum_b, out + outElems);
    }
}

// Round 14
// 197.950 us; speedup vs baseline: 2.0549x; 1.1399x over previous
//
#include <hip/hip_runtime.h>

#define OUTN 8192
#define INN  4096
#define BN   128

namespace {

typedef __attribute__((ext_vector_type(8))) short bf16x8;   // 8 bf16 (4 VGPRs)
typedef __attribute__((ext_vector_type(4))) float f32x4;

struct alignas(16) f4 { float v[4]; };
struct alignas(8)  h4 { short v[4]; };

constexpr float C_HLOG2PI = 0.91893853f;   // 0.5*log(2*pi)
constexpr float C_LN2     = 0.69314718f;

__device__ __forceinline__ short f2bf(float f) {
    unsigned u = __float_as_uint(f);
    u += 0x7fffu + ((u >> 16) & 1u);       // round-to-nearest-even
    return (short)(u >> 16);
}

// ---- full-form helpers (bias path only) ----
__device__ __forceinline__ float prior_lp(float w) {
    float lp1 = -0.5f * w * w - C_HLOG2PI;
    float a   = w * 400.0f;
    float lp2 = -0.5f * a * a + 5.0725261f;
    return __logf(0.5f * __expf(lp1) + 0.5f * __expf(lp2));
}
__device__ __forceinline__ float post_lp(float w, float pi_, float s1, float ls1,
                                         float s2, float ls2) {
    float u1  = __fdividef(w, s1);
    float u2  = __fdividef(w, s2);
    float lq1 = -0.5f * u1 * u1 - ls1 - C_HLOG2PI;
    float lq2 = -0.5f * u2 * u2 - ls2 - C_HLOG2PI;
    return __logf(pi_ * __expf(lq1) + (1.0f - pi_) * __expf(lq2));
}
__device__ __forceinline__ float sample_w(float pi_, float rho1, float rho2, float ep,
                                          float g0, float g1,
                                          float& s1, float& ls1, float& s2, float& ls2) {
    s1  = __logf(1.0f + __expf(rho1));
    s2  = __logf(1.0f + __expf(rho2));
    ls1 = __logf(s1);
    ls2 = __logf(s2);
    bool mode1 = ((1.0f - pi_) + g1) > (pi_ + g0);
    return (mode1 ? s1 : s2) * ep;
}

constexpr int OT = 32;     // output rows per tile
constexpr int KC = 32;     // K-chunk (== MFMA K)
constexpr int NT = 256;
constexpr int KSTR = 40;   // bf16 LDS row stride (80 B: 16B-aligned, bank-spread)

// ---- fused prep: blocks 0..255 cast x->bf16 ONCE; blocks 256..287 sample bias ----
// (R13 lesson: inlining the cast into main re-converts x NSx256 times and puts
//  the conversion inside the barrier-locked staging region — net loss.)
__global__ __launch_bounds__(256)
void prep(const float* __restrict__ x, short* __restrict__ xb,
          const float* __restrict__ b_pi, const float* __restrict__ b_rho1,
          const float* __restrict__ b_rho2, const float* __restrict__ eps_b,
          const float* __restrict__ gum_b,
          float* __restrict__ bias_vals, float* __restrict__ bpart)
{
    __shared__ float red[8];
    const int tid = threadIdx.x;
    if (blockIdx.x < 256) {
        const int i = (blockIdx.x * 256 + tid) * 8;
        f4 a = *(const f4*)&x[i];
        f4 b = *(const f4*)&x[i + 4];
        h4 o0, o1;
        #pragma unroll
        for (int j = 0; j < 4; ++j) { o0.v[j] = f2bf(a.v[j]); o1.v[j] = f2bf(b.v[j]); }
        *(h4*)&xb[i]     = o0;
        *(h4*)&xb[i + 4] = o1;
        return;
    }
    const int bb = blockIdx.x - 256;           // 0..31
    const int o = bb * 256 + tid;
    float pi_ = b_pi[o], rho1 = b_rho1[o], rho2 = b_rho2[o], ep = eps_b[o];
    float g0 = gum_b[2*o], g1 = gum_b[2*o + 1];
    float s1, ls1, s2, ls2;
    float w = sample_w(pi_, rho1, rho2, ep, g0, g1, s1, ls1, s2, ls2);
    bias_vals[o] = w;
    float pa = prior_lp(w);
    float qa = post_lp(w, pi_, s1, ls1, s2, ls2);
    #pragma unroll
    for (int off = 32; off; off >>= 1) {
        pa += __shfl_down(pa, off);
        qa += __shfl_down(qa, off);
    }
    const int wave = tid >> 6;
    if ((tid & 63) == 0) { red[wave] = pa; red[4 + wave] = qa; }
    __syncthreads();
    if (tid == 0) {
        bpart[2*bb    ] = red[0] + red[1] + red[2] + red[3];
        bpart[2*bb + 1] = red[4] + red[5] + red[6] + red[7];
    }
}

// CHAMPION structure (R8, 201.5 us): 2x __syncthreads per chunk, single-
// buffered LDS, prefetch issued after barrier 2, one stream generation.
// Every deviation tried (raw-barrier dbuf, KC=64 burst, depth-2 gens,
// loads-across-barrier, inline x-cast) regressed: >~64 live VGPRs spills
// (R10/R11/R12), fusion multiplies conversion work (R13). The compiler owns
// the schedule at this register pressure; do not restructure the loop.
__global__ __launch_bounds__(NT, 6)
void bayes_main(const short* __restrict__ xb,      // x in bf16, [BN][INN]
                const float* __restrict__ w_pi,
                const float* __restrict__ w_rho1,
                const float* __restrict__ w_rho2,
                const float* __restrict__ eps_w,
                const float* __restrict__ gum_w,
                const float* __restrict__ bias,    // non-null only when NS==1
                float* __restrict__ out,
                float* __restrict__ pbuf,
                float* __restrict__ partials,
                int NS)
{
    __shared__ alignas(16) short Wt[OT][KSTR];   // W tile [o][k] bf16
    __shared__ alignas(16) short Xs[BN][KSTR];   // x tile [b][k] bf16
    __shared__ float red[8];

    const int tid   = threadIdx.x;
    const int split = blockIdx.x >> 8;
    const int tile  = blockIdx.x & 255;
    const int o0    = tile * OT;

    // non-uniform K-split: 128 chunks over NS splits
    const int baseCh = 128 / NS;
    const int remCh  = 128 % NS;
    const int nch    = baseCh + (split < remCh ? 1 : 0);
    const int ch0    = split * baseCh + (split < remCh ? split : remCh);
    const int k0     = ch0 * KC;

    float* outp = (split == 0) ? out : pbuf + (size_t)(split - 1) * ((size_t)BN * OUTN);

    const int c = tid & 7;     // k-quad index
    const int r = tid >> 3;    // o-row index 0..31

    const size_t wbase = (size_t)(o0 + r) * INN + k0;
    const f4* pi4 = (const f4*)(w_pi   + wbase) + c;
    const f4* r14 = (const f4*)(w_rho1 + wbase) + c;
    const f4* r24 = (const f4*)(w_rho2 + wbase) + c;
    const f4* ep4 = (const f4*)(eps_w  + wbase) + c;
    const f4* gm4 = (const f4*)(gum_w  + 2 * wbase) + 2 * c;

    // x staging: thread covers row xrr, 16-short half xcc
    const int xrr = tid >> 1;           // 0..127
    const int xcc = (tid & 1) * 16;     // 0 or 16
    const short* xsrc = xb + (size_t)xrr * INN + k0 + xcc;

    f32x4 acc00 = {0.f,0.f,0.f,0.f}, acc01 = {0.f,0.f,0.f,0.f};
    f32x4 acc10 = {0.f,0.f,0.f,0.f}, acc11 = {0.f,0.f,0.f,0.f};
    float priorAcc = 0.0f, postAcc = 0.0f;

    // MFMA lane geometry
    const int wv_  = tid >> 6;          // wave 0..3 -> b-slice 32*wv_
    const int lane = tid & 63;
    const int lrow = lane & 15;
    const int lgo  = (lane >> 4) * 8;   // bf16 col offset of this lane's frag

    // prologue prefetch: chunk 0
    f4 vpi = pi4[0], vr1 = r14[0], vr2 = r24[0], vep = ep4[0];
    f4 vga = gm4[0], vgb = gm4[1];
    bf16x8 xv0 = *(const bf16x8*)(xsrc);
    bf16x8 xv1 = *(const bf16x8*)(xsrc + 8);

    #pragma unroll 1
    for (int t = 0; t < nch; ++t) {
        // --- sample 4 weights + accumulate log-probs (LSE, consts folded) ---
        h4 wb;
        #pragma unroll
        for (int i = 0; i < 4; ++i) {
            const f4& g = (i < 2) ? vga : vgb;
            float g0 = g.v[(i & 1) * 2], g1 = g.v[(i & 1) * 2 + 1];
            float pi_ = vpi.v[i], ep = vep.v[i];
            float s1  = __logf(1.0f + __expf(vr1.v[i]));
            float s2  = __logf(1.0f + __expf(vr2.v[i]));
            float ls1 = __logf(s1), ls2 = __logf(s2);
            bool  m1  = ((1.0f - pi_) + g1) > (pi_ + g0);
            float sm  = m1 ? s1 : s2;
            float so  = m1 ? s2 : s1;
            float lsm = m1 ? ls1 : ls2;
            float lso = m1 ? ls2 : ls1;
            float wm  = m1 ? pi_ : 1.0f - pi_;
            float w   = sm * ep;
            wb.v[i] = f2bf(w);
            float wsq = w * w;
            float dlp = 5.9914645f - 79999.5f * wsq;
            priorAcc += -0.5f * wsq + __logf(1.0f + __expf(dlp));   // -C-ln2 folded
            float uo   = __fdividef(w, so);
            float epsq = ep * ep;
            float dlq  = 0.5f * (epsq - uo * uo) + (lsm - lso);
            postAcc += -0.5f * epsq - lsm
                       + __logf(wm + (1.0f - wm) * __expf(dlq));    // -C folded
        }

        __syncthreads();             // previous chunk's frag reads done
        *(h4*)&Wt[r][4 * c] = wb;
        *(bf16x8*)&Xs[xrr][xcc]     = xv0;
        *(bf16x8*)&Xs[xrr][xcc + 8] = xv1;
        __syncthreads();             // tiles ready

        // --- prefetch t+1 (after the barrier: no vmcnt(0)-drain at s_barrier;
        //     latency covered by MFMA phase + 5 other resident blocks) ---
        const int tn = (t + 1 < nch) ? t + 1 : 0;
        vpi = pi4[8*tn]; vr1 = r14[8*tn]; vr2 = r24[8*tn]; vep = ep4[8*tn];
        vga = gm4[16*tn]; vgb = gm4[16*tn + 1];
        xv0 = *(const bf16x8*)(xsrc + 32*tn);
        xv1 = *(const bf16x8*)(xsrc + 32*tn + 8);

        // --- MFMA: A = x tile (M=b), B = W tile (N=o), K=32 ---
        bf16x8 a0 = *(const bf16x8*)&Xs[32 * wv_      + lrow][lgo];
        bf16x8 a1 = *(const bf16x8*)&Xs[32 * wv_ + 16 + lrow][lgo];
        bf16x8 b0 = *(const bf16x8*)&Wt[lrow     ][lgo];
        bf16x8 b1 = *(const bf16x8*)&Wt[16 + lrow][lgo];
        acc00 = __builtin_amdgcn_mfma_f32_16x16x32_bf16(a0, b0, acc00, 0, 0, 0);
        acc01 = __builtin_amdgcn_mfma_f32_16x16x32_bf16(a0, b1, acc01, 0, 0, 0);
        acc10 = __builtin_amdgcn_mfma_f32_16x16x32_bf16(a1, b0, acc10, 0, 0, 0);
        acc11 = __builtin_amdgcn_mfma_f32_16x16x32_bf16(a1, b1, acc11, 0, 0, 0);
    }

    // fold per-element constants: prior -(C+ln2), post -C, 4*nch elems/thread
    {
        const float ne = (float)(4 * nch);
        priorAcc -= ne * (C_HLOG2PI + C_LN2);
        postAcc  -= ne * C_HLOG2PI;
    }

    // epilogue: C/D layout col=lane&15 (o), row=(lane>>4)*4+reg (b)
    {
        const int oc = o0 + lrow;
        const int bb = 32 * wv_ + (lane >> 4) * 4;
        const float bv0 = bias ? bias[oc]      : 0.0f;
        const float bv1 = bias ? bias[oc + 16] : 0.0f;
        #pragma unroll
        for (int j = 0; j < 4; ++j) {
            outp[(size_t)(bb      + j) * OUTN + oc     ] = acc00[j] + bv0;
            outp[(size_t)(bb      + j) * OUTN + oc + 16] = acc01[j] + bv1;
            outp[(size_t)(bb + 16 + j) * OUTN + oc     ] = acc10[j] + bv0;
            outp[(size_t)(bb + 16 + j) * OUTN + oc + 16] = acc11[j] + bv1;
        }
    }

    // deterministic block reduction of log-prob partials
    #pragma unroll
    for (int off = 32; off; off >>= 1) {
        priorAcc += __shfl_down(priorAcc, off);
        postAcc  += __shfl_down(postAcc, off);
    }
    if ((tid & 63) == 0) { red[wv_] = priorAcc; red[4 + wv_] = postAcc; }
    __syncthreads();
    if (tid == 0) {
        partials[2*blockIdx.x    ] = red[0] + red[1] + red[2] + red[3];
        partials[2*blockIdx.x + 1] = red[4] + red[5] + red[6] + red[7];
    }
}

// ---- fused reduce + final (block 0 also reduces the log-prob partials) ----
__global__ __launch_bounds__(256)
void reduce_final(float* __restrict__ out, const float* __restrict__ pbuf,
                  const float* __restrict__ bias, int nsplit,
                  const float* __restrict__ partials, int cnt,
                  float* __restrict__ out_scalars)
{
    const int tid = threadIdx.x;
    const size_t i = ((size_t)blockIdx.x * 256 + tid) * 4;   // 1024 blocks
    const int o = (int)(i & (OUTN - 1));
    f4 a  = *(const f4*)&out[i];
    f4 bq = *(const f4*)&bias[o];
    #pragma unroll 1
    for (int s = 0; s < nsplit - 1; ++s) {
        f4 p = *(const f4*)&pbuf[(size_t)s * ((size_t)BN * OUTN) + i];
        #pragma unroll
        for (int j = 0; j < 4; ++j) a.v[j] += p.v[j];
    }
    #pragma unroll
    for (int j = 0; j < 4; ++j) a.v[j] += bq.v[j];
    *(f4*)&out[i] = a;

    if (blockIdx.x == 0) {
        __shared__ double sp[4], sq[4];
        double p = 0.0, q = 0.0;
        for (int j = tid; j < cnt; j += 256) {
            p += (double)partials[2*j];
            q += (double)partials[2*j + 1];
        }
        #pragma unroll
        for (int off = 32; off; off >>= 1) {
            p += __shfl_down(p, off);
            q += __shfl_down(q, off);
        }
        const int wave = tid >> 6;
        if ((tid & 63) == 0) { sp[wave] = p; sq[wave] = q; }
        __syncthreads();
        if (tid == 0) {
            out_scalars[0] = (float)(sp[0] + sp[1] + sp[2] + sp[3]);
            out_scalars[1] = (float)(sq[0] + sq[1] + sq[2] + sq[3]);
        }
    }
}

// NS==1 fallback final (no reduce pass)
__global__ __launch_bounds__(256)
void bayes_final(const float* __restrict__ partials, int cnt,
                 float* __restrict__ out_scalars)
{
    __shared__ double sp[4], sq[4];
    const int tid = threadIdx.x;
    double p = 0.0, q = 0.0;
    for (int j = tid; j < cnt; j += 256) {
        p += (double)partials[2*j];
        q += (double)partials[2*j + 1];
    }
    #pragma unroll
    for (int off = 32; off; off >>= 1) {
        p += __shfl_down(p, off);
        q += __shfl_down(q, off);
    }
    const int wave = tid >> 6;
    if ((tid & 63) == 0) { sp[wave] = p; sq[wave] = q; }
    __syncthreads();
    if (tid == 0) {
        out_scalars[0] = (float)(sp[0] + sp[1] + sp[2] + sp[3]);
        out_scalars[1] = (float)(sq[0] + sq[1] + sq[2] + sq[3]);
    }
}

} // namespace

extern "C" void kernel_launch(void* const* d_in, const int* in_sizes, int n_in,
                              void* d_out, int out_size, void* d_ws, size_t ws_size,
                              hipStream_t stream) {
    (void)in_sizes; (void)n_in; (void)out_size;
    const float* x      = (const float*)d_in[0];
    const float* w_pi   = (const float*)d_in[1];
    const float* w_rho1 = (const float*)d_in[2];
    const float* w_rho2 = (const float*)d_in[3];
    const float* b_pi   = (const float*)d_in[4];
    const float* b_rho1 = (const float*)d_in[5];
    const float* b_rho2 = (const float*)d_in[6];
    const float* eps_w  = (const float*)d_in[7];
    const float* eps_b  = (const float*)d_in[8];
    const float* gum_w  = (const float*)d_in[9];
    const float* gum_b  = (const float*)d_in[10];

    float* out = (float*)d_out;
    float* ws  = (float*)d_ws;
    // ws layout (floats):
    //   [0, 8192)           bias values
    //   [8192, 16384)       logp partials: main blocks (2*256*NS), then bias blocks
    //   [16384, 540672)     x in bf16 (524288 shorts)
    //   [540672, ...)       (NS-1) partial GEMM outputs, 1048576 floats each
    float* bias_vals = ws;
    float* partials  = ws + 8192;
    short* xb        = (short*)(ws + 16384);
    float* pbuf      = ws + 540672;

    const size_t outElems = (size_t)BN * OUTN;
    int NS = 1;
    if      (ws_size >= (540672 + 5 * outElems) * sizeof(float)) NS = 6;
    else if (ws_size >= (540672 + 3 * outElems) * sizeof(float)) NS = 4;
    else if (ws_size >= (540672 + 1 * outElems) * sizeof(float)) NS = 2;

    float* bpart = partials + 2 * 256 * NS;
    const int cnt = 256 * NS + 32;

    prep<<<288, 256, 0, stream>>>(x, xb, b_pi, b_rho1, b_rho2, eps_b, gum_b,
                                  bias_vals, bpart);

    if (NS == 1) {
        bayes_main<<<256, NT, 0, stream>>>(xb, w_pi, w_rho1, w_rho2, eps_w, gum_w,
                                           bias_vals, out, pbuf, partials, 1);
        bayes_final<<<1, 256, 0, stream>>>(partials, cnt, out + outElems);
    } else {
        bayes_main<<<256 * NS, NT, 0, stream>>>(xb, w_pi, w_rho1, w_rho2, eps_w, gum_w,
                                                nullptr, out, pbuf, partials, NS);
        reduce_final<<<(int)(outElems / 4 / 256), 256, 0, stream>>>(
            out, pbuf, bias_vals, NS, partials, cnt, out + outElems);
    }
}